// Round 10
// baseline (159.344 us; speedup 1.0000x reference)
//
#include <hip/hip_runtime.h>
#include <math.h>

#define H 2048
#define V 50257
#define NTHR 256
#define LB 1024           // logits blocks: 4/CU x 256 CU co-resident (32KB LDS)
#define NW (LB * 4)       // 4096 waves
#define ROWS_BASE 12      // 12*4096 = 49152; tail 1105 rows
#define TAIL (V - ROWS_BASE * NW)   // 1105

typedef unsigned long long u64;

#if defined(__has_builtin)
#if __has_builtin(__builtin_amdgcn_global_load_lds)
#define HAS_GLL 1
#endif
#endif
#ifndef HAS_GLL
#define HAS_GLL 0
#endif

__device__ __forceinline__ float wave_reduce_sum(float v) {
#pragma unroll
    for (int off = 32; off > 0; off >>= 1)
        v += __shfl_down(v, off, 64);
    return v;
}

__device__ __forceinline__ void online_comb(float& m, float& s, float om, float os) {
    float M = fmaxf(m, om);
    s = s * __expf(m - M) + os * __expf(om - M);
    m = M;
}

#if HAS_GLL
__device__ __forceinline__ void gl2lds16(const void* g, void* l) {
    __builtin_amdgcn_global_load_lds(
        (const __attribute__((address_space(1))) void*)g,
        (__attribute__((address_space(3))) void*)l, 16, 0, 0);
}
#endif

// ---------------------------------------------------------------------------
// GRU step, embed fused (R5/R8-proven). Resets the LB partials slots.
// ---------------------------------------------------------------------------
__global__ __launch_bounds__(384) void k_gru(
    const int* __restrict__ idx_p, const float* __restrict__ emb,
    const float* __restrict__ hid,
    const float* __restrict__ w_ih, const float* __restrict__ w_hh,
    const float* __restrict__ b_ih, const float* __restrict__ b_hh,
    float* __restrict__ hnew_ws, float* __restrict__ hnew_out,
    u64* __restrict__ partials) {
    __shared__ float xs[H];
    __shared__ float hs[H];
    __shared__ float partial[6][2];
    int tid = threadIdx.x;

    if (tid == 0) partials[blockIdx.x] = 0ull;   // 1024 blocks cover LB slots

    long idx = (long)idx_p[0];
    const float4* embrow = (const float4*)(emb + idx * (long)H);
    for (int i = tid; i < H / 4; i += 384) {
        float4 e = embrow[i];
        e.x = fmaxf(e.x, 0.f); e.y = fmaxf(e.y, 0.f);
        e.z = fmaxf(e.z, 0.f); e.w = fmaxf(e.w, 0.f);
        ((float4*)xs)[i] = e;
        ((float4*)hs)[i] = ((const float4*)hid)[i];
    }
    __syncthreads();

    int wid = tid >> 6, lane = tid & 63;
    int gate = wid % 3;
    const float* W   = (wid < 3) ? w_ih : w_hh;
    const float* vec = (wid < 3) ? xs : hs;
    int j0 = blockIdx.x, j1 = blockIdx.x + 1024;
    const float4* r0 = (const float4*)(W + ((size_t)gate * H + j0) * (size_t)H);
    const float4* r1 = (const float4*)(W + ((size_t)gate * H + j1) * (size_t)H);

    float4 vreg[8];
#pragma unroll
    for (int it = 0; it < 8; ++it)
        vreg[it] = ((const float4*)vec)[it * 64 + lane];

    float a0 = 0.f, a1 = 0.f;
#pragma unroll
    for (int it = 0; it < 8; ++it) {
        float4 wa = r0[it * 64 + lane];
        float4 wb = r1[it * 64 + lane];
        a0 += wa.x * vreg[it].x + wa.y * vreg[it].y + wa.z * vreg[it].z + wa.w * vreg[it].w;
        a1 += wb.x * vreg[it].x + wb.y * vreg[it].y + wb.z * vreg[it].z + wb.w * vreg[it].w;
    }
    a0 = wave_reduce_sum(a0);
    a1 = wave_reduce_sum(a1);
    if (lane == 0) { partial[wid][0] = a0; partial[wid][1] = a1; }
    __syncthreads();

    if (tid < 2) {
        int j = (tid == 0) ? j0 : j1;
        float i_r = partial[0][tid] + b_ih[j];
        float i_z = partial[1][tid] + b_ih[H + j];
        float i_n = partial[2][tid] + b_ih[2 * H + j];
        float h_r = partial[3][tid] + b_hh[j];
        float h_z = partial[4][tid] + b_hh[H + j];
        float h_n = partial[5][tid] + b_hh[2 * H + j];
        float r = 1.f / (1.f + expf(-(i_r + h_r)));
        float z = 1.f / (1.f + expf(-(i_z + h_z)));
        float n = tanhf(i_n + r * h_n);
        float hv = (1.f - z) * n + z * hs[j];
        hnew_ws[j] = hv;
        hnew_out[j] = hv;
    }
}

// ---------------------------------------------------------------------------
// Vocab projection + log-softmax. Half-row (4KB) DMA pipeline, 16 waves/CU:
// per wave, 2 x 4KB LDS slots; unit u = (row u>>1, half u&1); steady state
// keeps 2 units (8 loads) in flight; 16 waves/CU -> 64-128KB in flight/CU.
// hnew lives in registers straight from global. Fence-free partial exchange.
// ---------------------------------------------------------------------------
__global__ __launch_bounds__(NTHR, 4) void k_logits_fused(
    const float* __restrict__ out_w, const float* __restrict__ out_b,
    const float* __restrict__ hnew, float* __restrict__ out,
    u64* __restrict__ partials) {
    __shared__ float stage[4][2][1024];   // 32 KB: per-wave double buffer
    __shared__ float l_lds[4][13];
    __shared__ float pm[4], ps[4];
    __shared__ float c_s;
    const int tid = threadIdx.x, wid = tid >> 6, lane = tid & 63;
    const int gw = blockIdx.x * 4 + wid;      // 0..4095
    const int nrows = ROWS_BASE + (gw < TAIL ? 1 : 0);

    // hnew fragment + this wave's biases, straight from global (L2-hot)
    float4 vreg[8];
#pragma unroll
    for (int it = 0; it < 8; ++it)
        vreg[it] = ((const float4*)hnew)[it * 64 + lane];
    float bias = 0.f;
    if (lane < nrows) {
        int r = (lane < ROWS_BASE) ? (gw + lane * NW) : (ROWS_BASE * NW + gw);
        bias = out_b[r];
    }

    float m = -INFINITY, s = 0.f;

#if HAS_GLL
    float* slot0 = &stage[wid][0][0];
    float* slot1 = &stage[wid][1][0];
    // issue unit u (4KB half-row): 4 x global_load_lds dwordx4 into slot u&1
    auto issue_unit = [&](int u) {
        int k = u >> 1, h = u & 1;
        int r = (k < ROWS_BASE) ? (gw + k * NW) : (ROWS_BASE * NW + gw);
        const char* gb = (const char*)(out_w + (size_t)r * H + h * 1024) + lane * 16;
        char* lb = (char*)((u & 1) ? slot1 : slot0);
#pragma unroll
        for (int c = 0; c < 4; ++c)
            gl2lds16(gb + c * 1024, lb + c * 1024);
    };

    const int U = 2 * nrows;
    issue_unit(0);
    issue_unit(1);
    float acc = 0.f;
#pragma unroll 1
    for (int u = 0; u < U; ++u) {
        if (u == U - 1) {
            asm volatile("s_waitcnt vmcnt(0)" ::: "memory");
        } else {
            asm volatile("s_waitcnt vmcnt(4)" ::: "memory");
        }
        __builtin_amdgcn_sched_barrier(0);
        const float4* s4 = (const float4*)((u & 1) ? slot1 : slot0);
        const int hb = (u & 1) * 4;
#pragma unroll
        for (int it = 0; it < 4; ++it) {
            float4 w4 = s4[it * 64 + lane];
            acc += w4.x * vreg[hb + it].x + w4.y * vreg[hb + it].y +
                   w4.z * vreg[hb + it].z + w4.w * vreg[hb + it].w;
        }
        if (u & 1) {
            int k = u >> 1;
            float t = wave_reduce_sum(acc);
            float bk = __shfl(bias, k, 64);
            if (lane == 0) {
                float l = t + bk;
                l_lds[wid][k] = l;
                online_comb(m, s, l, 1.0f);
            }
            acc = 0.f;
        }
        if (u + 2 < U) issue_unit(u + 2);
    }
#else
    // fallback: register-destination dot (R8 path)
#pragma unroll 1
    for (int k = 0; k < nrows; ++k) {
        int r = (k < ROWS_BASE) ? (gw + k * NW) : (ROWS_BASE * NW + gw);
        const float4* row = (const float4*)(out_w + (size_t)r * H);
        float acc = 0.f;
#pragma unroll
        for (int it = 0; it < 8; ++it) {
            float4 w4 = row[it * 64 + lane];
            acc += w4.x * vreg[it].x + w4.y * vreg[it].y + w4.z * vreg[it].z + w4.w * vreg[it].w;
        }
        acc = wave_reduce_sum(acc);
        float bk = __shfl(bias, k, 64);
        if (lane == 0) {
            float l = acc + bk;
            l_lds[wid][k] = l;
            online_comb(m, s, l, 1.0f);
        }
    }
#endif

    if (lane == 0) { pm[wid] = m; ps[wid] = s; }
    __syncthreads();

    // publish packed (m, sumexp): one relaxed atomic, no fence
    if (tid == 0) {
        float M = pm[0], S = ps[0];
        online_comb(M, S, pm[1], ps[1]);
        online_comb(M, S, pm[2], ps[2]);
        online_comb(M, S, pm[3], ps[3]);
        u64 pk = ((u64)__float_as_uint(S) << 32) | (u64)__float_as_uint(M);
        __hip_atomic_store(&partials[blockIdx.x], pk, __ATOMIC_RELAXED,
                           __HIP_MEMORY_SCOPE_AGENT);
    }
    __syncthreads();

    // relaxed-poll all LB slots (4 per thread), merge online
    float mm = -INFINITY, ss = 0.f;
    for (int i = tid; i < LB; i += NTHR) {
        u64 pk;
        while ((pk = __hip_atomic_load(&partials[i], __ATOMIC_RELAXED,
                                       __HIP_MEMORY_SCOPE_AGENT)) == 0ull)
            __builtin_amdgcn_s_sleep(8);
        float pmv = __uint_as_float((unsigned)(pk & 0xffffffffu));
        float psv = __uint_as_float((unsigned)(pk >> 32));
        online_comb(mm, ss, pmv, psv);
    }
#pragma unroll
    for (int off = 32; off > 0; off >>= 1) {
        float om = __shfl_down(mm, off, 64);
        float os = __shfl_down(ss, off, 64);
        online_comb(mm, ss, om, os);
    }
    if (lane == 0) { pm[wid] = mm; ps[wid] = ss; }
    __syncthreads();
    if (tid == 0) {
        float M = pm[0], S = ps[0];
        online_comb(M, S, pm[1], ps[1]);
        online_comb(M, S, pm[2], ps[2]);
        online_comb(M, S, pm[3], ps[3]);
        c_s = M + logf(S);
    }
    __syncthreads();
    const float C = c_s;

    // write logp straight from LDS
    if (lane < ROWS_BASE) {
        out[gw + lane * NW] = l_lds[wid][lane] - C;
    } else if (lane == ROWS_BASE && gw < TAIL) {
        out[ROWS_BASE * NW + gw] = l_lds[wid][ROWS_BASE] - C;
    }
}

extern "C" void kernel_launch(void* const* d_in, const int* in_sizes, int n_in,
                              void* d_out, int out_size, void* d_ws, size_t ws_size,
                              hipStream_t stream) {
    const int*   idx    = (const int*)d_in[0];
    const float* hidden = (const float*)d_in[1];
    const float* emb    = (const float*)d_in[2];
    const float* w_ih   = (const float*)d_in[3];
    const float* w_hh   = (const float*)d_in[4];
    const float* b_ih   = (const float*)d_in[5];
    const float* b_hh   = (const float*)d_in[6];
    const float* out_w  = (const float*)d_in[7];
    const float* out_b  = (const float*)d_in[8];

    float* out = (float*)d_out;                 // [V logp][H hnew]
    float* ws  = (float*)d_ws;
    float* hnew     = ws;                       // H floats
    u64*   partials = (u64*)(ws + H);           // LB u64

    k_gru<<<1024, 384, 0, stream>>>(idx, emb, hidden, w_ih, w_hh, b_ih, b_hh,
                                    hnew, out + V, partials);
    k_logits_fused<<<LB, NTHR, 0, stream>>>(out_w, out_b, hnew, out, partials);
}

// Round 11
// 97.170 us; speedup vs baseline: 1.6398x; 1.6398x over previous
//
#include <hip/hip_runtime.h>
#include <math.h>

#define H 2048
#define V 50257
#define NTHR 256
#define LB 512            // logits blocks: 2/CU x 256 CU co-resident (LDS-limited)
#define NW (LB * 4)       // 2048 waves
#define ROWS_BASE 24      // 24*2048 = 49152; tail 1105 rows
#define TAIL (V - ROWS_BASE * NW)   // 1105

typedef unsigned long long u64;

#if defined(__has_builtin)
#if __has_builtin(__builtin_amdgcn_global_load_lds)
#define HAS_GLL 1
#endif
#endif
#ifndef HAS_GLL
#define HAS_GLL 0
#endif

__device__ __forceinline__ float wave_reduce_sum(float v) {
#pragma unroll
    for (int off = 32; off > 0; off >>= 1)
        v += __shfl_down(v, off, 64);
    return v;
}

__device__ __forceinline__ void online_comb(float& m, float& s, float om, float os) {
    float M = fmaxf(m, om);
    s = s * __expf(m - M) + os * __expf(om - M);
    m = M;
}

#if HAS_GLL
__device__ __forceinline__ void gl2lds16(const void* g, void* l) {
    __builtin_amdgcn_global_load_lds(
        (const __attribute__((address_space(1))) void*)g,
        (__attribute__((address_space(3))) void*)l, 16, 0, 0);
}
#endif

// ---------------------------------------------------------------------------
// GRU step, embed fused (R5/R8-proven). Resets the LB partials slots.
// ---------------------------------------------------------------------------
__global__ __launch_bounds__(384) void k_gru(
    const int* __restrict__ idx_p, const float* __restrict__ emb,
    const float* __restrict__ hid,
    const float* __restrict__ w_ih, const float* __restrict__ w_hh,
    const float* __restrict__ b_ih, const float* __restrict__ b_hh,
    float* __restrict__ hnew_ws, float* __restrict__ hnew_out,
    u64* __restrict__ partials) {
    __shared__ float xs[H];
    __shared__ float hs[H];
    __shared__ float partial[6][2];
    int tid = threadIdx.x;

    if (tid == 0 && blockIdx.x < LB) partials[blockIdx.x] = 0ull;

    long idx = (long)idx_p[0];
    const float4* embrow = (const float4*)(emb + idx * (long)H);
    for (int i = tid; i < H / 4; i += 384) {
        float4 e = embrow[i];
        e.x = fmaxf(e.x, 0.f); e.y = fmaxf(e.y, 0.f);
        e.z = fmaxf(e.z, 0.f); e.w = fmaxf(e.w, 0.f);
        ((float4*)xs)[i] = e;
        ((float4*)hs)[i] = ((const float4*)hid)[i];
    }
    __syncthreads();

    int wid = tid >> 6, lane = tid & 63;
    int gate = wid % 3;
    const float* W   = (wid < 3) ? w_ih : w_hh;
    const float* vec = (wid < 3) ? xs : hs;
    int j0 = blockIdx.x, j1 = blockIdx.x + 1024;
    const float4* r0 = (const float4*)(W + ((size_t)gate * H + j0) * (size_t)H);
    const float4* r1 = (const float4*)(W + ((size_t)gate * H + j1) * (size_t)H);

    float4 vreg[8];
#pragma unroll
    for (int it = 0; it < 8; ++it)
        vreg[it] = ((const float4*)vec)[it * 64 + lane];

    float a0 = 0.f, a1 = 0.f;
#pragma unroll
    for (int it = 0; it < 8; ++it) {
        float4 wa = r0[it * 64 + lane];
        float4 wb = r1[it * 64 + lane];
        a0 += wa.x * vreg[it].x + wa.y * vreg[it].y + wa.z * vreg[it].z + wa.w * vreg[it].w;
        a1 += wb.x * vreg[it].x + wb.y * vreg[it].y + wb.z * vreg[it].z + wb.w * vreg[it].w;
    }
    a0 = wave_reduce_sum(a0);
    a1 = wave_reduce_sum(a1);
    if (lane == 0) { partial[wid][0] = a0; partial[wid][1] = a1; }
    __syncthreads();

    if (tid < 2) {
        int j = (tid == 0) ? j0 : j1;
        float i_r = partial[0][tid] + b_ih[j];
        float i_z = partial[1][tid] + b_ih[H + j];
        float i_n = partial[2][tid] + b_ih[2 * H + j];
        float h_r = partial[3][tid] + b_hh[j];
        float h_z = partial[4][tid] + b_hh[H + j];
        float h_n = partial[5][tid] + b_hh[2 * H + j];
        float r = 1.f / (1.f + expf(-(i_r + h_r)));
        float z = 1.f / (1.f + expf(-(i_z + h_z)));
        float n = tanhf(i_n + r * h_n);
        float hv = (1.f - z) * n + z * hs[j];
        hnew_ws[j] = hv;
        hnew_out[j] = hv;
    }
}

// ---------------------------------------------------------------------------
// Vocab projection + log-softmax. LDS-staged deep pipeline (R9-proven):
// per wave, rows arrive via global_load_lds (async DMA, 2 x 8KB slots,
// 16 outstanding dwordx4 -> 16KB in flight/wave), dot computed from LDS.
// Fence-free relaxed-atomic partial exchange (R8-proven).
// ---------------------------------------------------------------------------
__global__ __launch_bounds__(NTHR, 2) void k_logits_fused(
    const float* __restrict__ out_w, const float* __restrict__ out_b,
    const float* __restrict__ hnew, float* __restrict__ out,
    u64* __restrict__ partials) {
    __shared__ float hsm[H];
    __shared__ float stage[4][2][H];    // 64 KB: per-wave double buffer
    __shared__ float l_lds[4][25];
    __shared__ float pm[4], ps[4];
    __shared__ float c_s;
    const int tid = threadIdx.x, wid = tid >> 6, lane = tid & 63;
    const int gw = blockIdx.x * 4 + wid;      // 0..2047
    const int nrows = ROWS_BASE + (gw < TAIL ? 1 : 0);

    // stage hnew; preload this wave's biases (lane k holds bias of row k)
    for (int i = tid; i < H / 4; i += NTHR)
        ((float4*)hsm)[i] = ((const float4*)hnew)[i];
    float bias = 0.f;
    if (lane < nrows) {
        int r = (lane < ROWS_BASE) ? (gw + lane * NW) : (ROWS_BASE * NW + gw);
        bias = out_b[r];
    }
    asm volatile("" :: "v"(bias));   // force load now; drained by barrier
    __syncthreads();                 // vmcnt(0): FIFO empty at pipeline start

    float4 vreg[8];
#pragma unroll
    for (int it = 0; it < 8; ++it)
        vreg[it] = ((const float4*)hsm)[it * 64 + lane];

    float* slot0 = &stage[wid][0][0];
    float* slot1 = &stage[wid][1][0];

    float m = -INFINITY, s = 0.f;

#if HAS_GLL
    // ---- issue row k into slot (k&1): 8 x global_load_lds dwordx4 ----
    auto issue_row = [&](int k) {
        int r = (k < ROWS_BASE) ? (gw + k * NW) : (ROWS_BASE * NW + gw);
        const char* gb = (const char*)(out_w + (size_t)r * H) + lane * 16;
        char* lb = (char*)((k & 1) ? slot1 : slot0);
#pragma unroll
        for (int c = 0; c < 8; ++c)
            gl2lds16(gb + c * 1024, lb + c * 1024);
    };

    issue_row(0);
    issue_row(1);
#pragma unroll 1
    for (int k = 0; k < nrows; ++k) {
        if (k == nrows - 1) {
            asm volatile("s_waitcnt vmcnt(0)" ::: "memory");
        } else {
            asm volatile("s_waitcnt vmcnt(8)" ::: "memory");
        }
        __builtin_amdgcn_sched_barrier(0);
        const float4* s4 = (const float4*)((k & 1) ? slot1 : slot0);
        float acc = 0.f;
#pragma unroll
        for (int it = 0; it < 8; ++it) {
            float4 w4 = s4[it * 64 + lane];
            acc += w4.x * vreg[it].x + w4.y * vreg[it].y + w4.z * vreg[it].z + w4.w * vreg[it].w;
        }
        acc = wave_reduce_sum(acc);
        float bk = __shfl(bias, k, 64);
        if (lane == 0) {
            float l = acc + bk;
            l_lds[wid][k] = l;
            online_comb(m, s, l, 1.0f);
        }
        if (k + 2 < nrows) issue_row(k + 2);
    }
#else
    // fallback: register-destination dot (R8 path)
#pragma unroll 1
    for (int k = 0; k < nrows; ++k) {
        int r = (k < ROWS_BASE) ? (gw + k * NW) : (ROWS_BASE * NW + gw);
        const float4* row = (const float4*)(out_w + (size_t)r * H);
        float acc = 0.f;
#pragma unroll
        for (int it = 0; it < 8; ++it) {
            float4 w4 = row[it * 64 + lane];
            acc += w4.x * vreg[it].x + w4.y * vreg[it].y + w4.z * vreg[it].z + w4.w * vreg[it].w;
        }
        acc = wave_reduce_sum(acc);
        float bk = __shfl(bias, k, 64);
        if (lane == 0) {
            float l = acc + bk;
            l_lds[wid][k] = l;
            online_comb(m, s, l, 1.0f);
        }
    }
#endif

    if (lane == 0) { pm[wid] = m; ps[wid] = s; }
    __syncthreads();

    // publish packed (m, sumexp): one relaxed atomic, no fence
    if (tid == 0) {
        float M = pm[0], S = ps[0];
        online_comb(M, S, pm[1], ps[1]);
        online_comb(M, S, pm[2], ps[2]);
        online_comb(M, S, pm[3], ps[3]);
        u64 pk = ((u64)__float_as_uint(S) << 32) | (u64)__float_as_uint(M);
        __hip_atomic_store(&partials[blockIdx.x], pk, __ATOMIC_RELAXED,
                           __HIP_MEMORY_SCOPE_AGENT);
    }
    __syncthreads();   // publish uses pm/ps before they're overwritten below

    // relaxed-poll all LB slots (2 per thread), merge online
    float mm = -INFINITY, ss = 0.f;
    for (int i = tid; i < LB; i += NTHR) {
        u64 pk;
        while ((pk = __hip_atomic_load(&partials[i], __ATOMIC_RELAXED,
                                       __HIP_MEMORY_SCOPE_AGENT)) == 0ull)
            __builtin_amdgcn_s_sleep(8);
        float pmv = __uint_as_float((unsigned)(pk & 0xffffffffu));
        float psv = __uint_as_float((unsigned)(pk >> 32));
        online_comb(mm, ss, pmv, psv);
    }
#pragma unroll
    for (int off = 32; off > 0; off >>= 1) {
        float om = __shfl_down(mm, off, 64);
        float os = __shfl_down(ss, off, 64);
        online_comb(mm, ss, om, os);
    }
    if (lane == 0) { pm[wid] = mm; ps[wid] = ss; }
    __syncthreads();
    if (tid == 0) {
        float M = pm[0], S = ps[0];
        online_comb(M, S, pm[1], ps[1]);
        online_comb(M, S, pm[2], ps[2]);
        online_comb(M, S, pm[3], ps[3]);
        c_s = M + logf(S);
    }
    __syncthreads();
    const float C = c_s;

    // write logp straight from LDS
    if (lane < ROWS_BASE) {
        out[gw + lane * NW] = l_lds[wid][lane] - C;
    } else if (lane == ROWS_BASE && gw < TAIL) {
        out[ROWS_BASE * NW + gw] = l_lds[wid][ROWS_BASE] - C;
    }
}

extern "C" void kernel_launch(void* const* d_in, const int* in_sizes, int n_in,
                              void* d_out, int out_size, void* d_ws, size_t ws_size,
                              hipStream_t stream) {
    const int*   idx    = (const int*)d_in[0];
    const float* hidden = (const float*)d_in[1];
    const float* emb    = (const float*)d_in[2];
    const float* w_ih   = (const float*)d_in[3];
    const float* w_hh   = (const float*)d_in[4];
    const float* b_ih   = (const float*)d_in[5];
    const float* b_hh   = (const float*)d_in[6];
    const float* out_w  = (const float*)d_in[7];
    const float* out_b  = (const float*)d_in[8];

    float* out = (float*)d_out;                 // [V logp][H hnew]
    float* ws  = (float*)d_ws;
    float* hnew     = ws;                       // H floats
    u64*   partials = (u64*)(ws + H);           // LB u64

    k_gru<<<1024, 384, 0, stream>>>(idx, emb, hidden, w_ih, w_hh, b_ih, b_hh,
                                    hnew, out + V, partials);
    k_logits_fused<<<LB, NTHR, 0, stream>>>(out_w, out_b, hnew, out, partials);
}